// Round 2
// baseline (7256.051 us; speedup 1.0000x reference)
//
#include <hip/hip_runtime.h>
#include <math.h>

// Problem constants (from reference)
#define RUNS  512
#define WAYS  5
#define SHOT  5
#define NSUP  25      // NS = WAYS*SHOT
#define NQ    75      // QS = WAYS*QUERIES
#define N0    100     // NS+QS
#define NF    105     // N0 + WAYS (extended with add_proto)
#define DIM   640
#define LAMB  10.0f
#define ALF   0.7f
#define UPD   0.6f
#define OT_EPSF 0.001f
#define OT_MAXIT 1000

#define NTILE 14          // ceil(105/8)
#define FCH_ROWS 112      // NTILE*8
#define FCH_STRIDE 36     // 32 dims + pad, multiple of 4 for float4
#define HALF 56           // GJ column-half width (2*56 >= 105, 56%4==0)
#define CHUNK 64          // sinkhorn trajectory chunk (bits in one ull)

// ---- workspace layout (words; everything line-padded, 16 KB total) ----
// WAKE(g)  : ctl[g*16]          g<64  (lines 0..63)   packed seq|found
// C1(g)    : ctl[1024 + g*16]   g<64  (lines 64..127) arrival level 1 (8 blocks)
// C2(s)    : ctl[2048 + s*16]   s<8   (lines 128..135) arrival level 2
// C0       : ctl[2176]                (line 136)       arrival root
// SLOT(b,g): ull at ctl+2304+(b*16+g)*16, b<2 bufs, g<16 (lines 144..175)
#define W_WAKE(g)  ((g) * 16)
#define W_C1(g)    (1024 + (g) * 16)
#define W_C2(s)    (2048 + (s) * 16)
#define W_C0       2176
#define W_SLOT(b,g) (2304 + ((b) * 16 + (g)) * 16)

struct __align__(16) Smem {
  float fch[FCH_ROWS * FCH_STRIDE]; // 4032 f @0 (16B aligned); reused as band[8][112]
  float pbuf[WAYS * DIM];           // 3200: prototypes live in LDS
  float rowk[112];                  // GJ: scaled pivot row
  float colk[112];                  // GJ: pivot column (colk[k]=0 trick)
  float Zm[NF * WAYS];              // 525
  float ent[NF];
  float fnorm[112];
  float dm[112];
  float rsumh[112];
  float dp[WAYS * WAYS];
  float pn[WAYS];
  float maskv[WAYS];
  float red[4];
  float pivotv;
  int foundsh;
  int ysl[NSUP];
};
static_assert(sizeof(Smem) <= 40 * 1024, "LDS: 2 blocks/CU (80KB of 160KB)");

__device__ __forceinline__ float wsum(float v) {
#pragma unroll
  for (int o = 32; o > 0; o >>= 1) v += __shfl_xor(v, o, 64);
  return v;
}
__device__ __forceinline__ float wmaxr(float v) {
#pragma unroll
  for (int o = 32; o > 0; o >>= 1) v = fmaxf(v, __shfl_xor(v, o, 64));
  return v;
}
// Deterministic block reductions (fixed tree order; NO float atomics)
__device__ __forceinline__ float bsum(float v, float* red, int tid) {
  v = wsum(v);
  __syncthreads();                   // WAR protection on red
  if ((tid & 63) == 0) red[tid >> 6] = v;
  __syncthreads();
  return (red[0] + red[1]) + (red[2] + red[3]);
}

// ---- contention-free grid barrier with found-broadcast ----
// Round-1 counters showed ~1.3 GB of fabric poll reads: 512 pollers spinning
// on ONE cacheline (ctl[0]) serialized at the coherence point (~40 us/barrier
// x ~96 sinkhorn chunks ~= 4 ms). This version:
//  * every contended word on its own 64B line (arrival counters, slots, wake)
//  * arrival: 3-level never-reset release fetch_add tree (8 per counter)
//  * the LAST arriver (root) ORs the 16 slot words, computes `found` once,
//    zeroes the slot buffer (reused at chunk bi+2; ordered: all chunk-bi ors
//    happened-before arrival(bi); zeroes drained by the RELEASE on the first
//    wake store; any block's next-next or happens after wake-read(bi+1)),
//    then stores 64 per-group wake words = seq | (found+1)<<16 (8 pollers
//    per line, no serialization). Monotone seq, no ABA; a poller cannot miss
//    seq s because root(s+1) requires this poller's arrival(s+1).
// Polls/loads are RELAXED agent-scope (coherence-point ops, no cache thrash).
__device__ __forceinline__ void gbar_found(Smem& sm, unsigned* ctl, unsigned& bi,
                                           int tid, int r, int buf, int base) {
  __syncthreads();
  if (tid == 0) {
    const unsigned tgt = 8u * bi + 7u;
    const unsigned seq = bi + 1u;
    int found = -1;
    bool isroot = false;
    unsigned a = __hip_atomic_fetch_add(&ctl[W_C1(r >> 3)], 1u,
                                        __ATOMIC_RELEASE, __HIP_MEMORY_SCOPE_AGENT);
    if (a == tgt) {
      unsigned b = __hip_atomic_fetch_add(&ctl[W_C2(r >> 6)], 1u,
                                          __ATOMIC_RELEASE, __HIP_MEMORY_SCOPE_AGENT);
      if (b == tgt) {
        unsigned c = __hip_atomic_fetch_add(&ctl[W_C0], 1u,
                                            __ATOMIC_RELEASE, __HIP_MEMORY_SCOPE_AGENT);
        if (c == tgt) isroot = true;
      }
    }
    if (isroot) {
      // all blocks arrived => all their slot fetch_ors are at the coherence
      // point (each or happens-before that block's RELEASE arrival RMW).
      unsigned long long m = 0ull;
#pragma unroll
      for (int g = 0; g < 16; g++)
        m |= __hip_atomic_load((unsigned long long*)(ctl + W_SLOT(buf, g)),
                               __ATOMIC_RELAXED, __HIP_MEMORY_SCOPE_AGENT);
      for (int p = 0; p < CHUNK; p++) {
        int k = base + p + 1;
        bool cond = (((m >> p) & 1ull) != 0ull) && (k <= OT_MAXIT);
        if (!cond) { found = p; break; }
      }
      // zero this slot buffer for reuse at chunk bi+2 (m already consumed,
      // so the loads have returned before these stores issue)
#pragma unroll
      for (int g = 0; g < 16; g++)
        __hip_atomic_store((unsigned long long*)(ctl + W_SLOT(buf, g)), 0ull,
                           __ATOMIC_RELAXED, __HIP_MEMORY_SCOPE_AGENT);
      unsigned pk = seq | ((unsigned)(found + 1) << 16);
      // first wake store RELEASE: vmcnt(0) drains the zero-stores before any
      // poller can observe a wake word; remaining stores relaxed (issued
      // strictly after the waitcnt, so they also follow the zeroes).
      __hip_atomic_store(&ctl[W_WAKE(0)], pk, __ATOMIC_RELEASE, __HIP_MEMORY_SCOPE_AGENT);
#pragma unroll 4
      for (int g = 1; g < 64; g++)
        __hip_atomic_store(&ctl[W_WAKE(g)], pk, __ATOMIC_RELAXED, __HIP_MEMORY_SCOPE_AGENT);
    } else {
      unsigned w;
      for (;;) {
        w = __hip_atomic_load(&ctl[W_WAKE(r >> 3)], __ATOMIC_RELAXED, __HIP_MEMORY_SCOPE_AGENT);
        if ((w & 0xffffu) >= seq) break;
        __builtin_amdgcn_s_sleep(8);
      }
      found = (int)((w >> 16) & 0xffu) - 1;
    }
    sm.foundsh = found;
    bi++;
  }
  __syncthreads();
}

// entropy per reference compute_entropy on a 5-vector (stride 1)
__device__ __forceinline__ float entropy5(const float* z) {
  float p[5]; float t = 0.f;
#pragma unroll
  for (int w = 0; w < 5; w++) { p[w] = z[w] + 1e-12f; t += p[w]; }
  float H = 0.f;
#pragma unroll
  for (int w = 0; w < 5; w++) { float q = p[w] / t; H -= q * logf(q); }
  return H / logf(5.0f);
}

__device__ __forceinline__ float loadF(const float* xs, const float* xq, int r, int i, int d) {
  return (i < NSUP) ? xs[(r * NSUP + i) * DIM + d] : xq[(r * NQ + (i - NSUP)) * DIM + d];
}

// Chunked-trajectory Sinkhorn with exact global iteration count.
// Publish ordering: tid0's fetch_or (relaxed) is drained by tid0's RELEASE
// arrival RMW in gbar_found (vmcnt(0) at the coherence point), so every or
// has completed before the root can observe full arrival.
__device__ void sinkhorn_wave(Smem& sm, unsigned* ctl,
                              unsigned& bi, int rowOff, int n, float cval,
                              bool clampLab, int tid, int r, int& sidx) {
  const int lane = tid & 63;
  const int wv = tid >> 6;
  float p0[5], p1[5], u0 = 0.f, u1 = 0.f;
  float q0[5], q1[5], v0 = 0.f, v1 = 0.f;
  bool e0 = false, e1 = false;
  int row0 = 0, y0 = -1;
  if (wv == 0) {
    row0 = lane;
    int row1 = lane + 64;
    e0 = row0 < n; e1 = row1 < n;
    y0 = (clampLab && row0 < NSUP) ? sm.ysl[row0] : -1;
#pragma unroll
    for (int w = 0; w < 5; w++) {
      p0[w] = e0 ? sm.Zm[(rowOff + row0) * 5 + w] : 0.f;
      p1[w] = e1 ? sm.Zm[(rowOff + row1) * 5 + w] : 0.f;
    }
  }
  // body: exactly the reference iteration (row-norm, col-norm, clamp)
  auto body = [&]() {
    float t0 = 0.f, t1 = 0.f;
#pragma unroll
    for (int w = 0; w < 5; w++) { t0 += p0[w]; t1 += p1[w]; }
    u0 = t0; u1 = t1;
    float i0 = e0 ? 1.0f / t0 : 0.f;
    float i1 = e1 ? 1.0f / t1 : 0.f;
#pragma unroll
    for (int w = 0; w < 5; w++) { p0[w] *= i0; p1[w] *= i1; }
#pragma unroll
    for (int w = 0; w < 5; w++) {
      float cs = wsum(p0[w] + p1[w]);
      float f = cval / cs;
      p0[w] *= f; p1[w] *= f;
    }
    if (y0 >= 0) {
#pragma unroll
      for (int w = 0; w < 5; w++) p0[w] = (y0 == w) ? 1.0f : 0.0f;
    }
  };

  int base = 0;
  while (true) {
    unsigned long long mask = 0ull;
    if (wv == 0) {
      // snapshot state after `base` bodies
#pragma unroll
      for (int w = 0; w < 5; w++) { q0[w] = p0[w]; q1[w] = p1[w]; }
      v0 = u0; v1 = u1;
#pragma unroll 1
      for (int p = 0; p < CHUNK; p++) {
        float t0 = 0.f, t1 = 0.f;
#pragma unroll
        for (int w = 0; w < 5; w++) { t0 += p0[w]; t1 += p1[w]; }
        float res = fmaxf(e0 ? fabsf(u0 - t0) : 0.f, e1 ? fabsf(u1 - t1) : 0.f);
        res = wmaxr(res);
        if (res > OT_EPSF) mask |= (1ull << p);
        body();
      }
      if (lane == 0)
        __hip_atomic_fetch_or((unsigned long long*)(ctl + W_SLOT(sidx & 1, r >> 5)), mask,
                              __ATOMIC_RELAXED, __HIP_MEMORY_SCOPE_AGENT);
    }
    gbar_found(sm, ctl, bi, tid, r, sidx & 1, base);
    int found = sm.foundsh;
    sidx++;
    if (found >= 0) {
      if (wv == 0) {
        // restore snapshot, replay exactly `found` bodies (total = base+found)
#pragma unroll
        for (int w = 0; w < 5; w++) { p0[w] = q0[w]; p1[w] = q1[w]; }
        u0 = v0; u1 = v1;
#pragma unroll 1
        for (int p = 0; p < found; p++) body();
#pragma unroll
        for (int w = 0; w < 5; w++) {
          if (e0) sm.Zm[(rowOff + row0) * 5 + w] = p0[w];
          if (e1) sm.Zm[(rowOff + lane + 64) * 5 + w] = p1[w];
        }
      }
      __syncthreads();
      return;
    }
    base += CHUNK;
  }
}

// init: zero barrier words + slots (16 KB region); sentinel out=-1
__global__ void init_kernel(unsigned* __restrict__ ctl, float* __restrict__ out) {
  int i = blockIdx.x * blockDim.x + threadIdx.x;
  if (i < 4096) __hip_atomic_store(&ctl[i], 0u, __ATOMIC_RELAXED, __HIP_MEMORY_SCOPE_AGENT);
  if (i < RUNS) out[i] = -1.0f;
}

__global__ __launch_bounds__(256, 2) void fsl_kernel(
    const float* __restrict__ xs, const float* __restrict__ xq,
    const int* __restrict__ ys, const int* __restrict__ yq,
    float* __restrict__ out, unsigned* __restrict__ ctl) {
  __shared__ Smem sm;
  const int tid = threadIdx.x;
  const int r = blockIdx.x;
  const int lane = tid & 63, wid = tid >> 6;
  unsigned bi = 0;
  int sidx = 0;

  // ---- persistent precompute ----
  for (int i = wid; i < N0; i += 4) {     // |f_i|^2, constant across epochs
    float p = 0.f;
    for (int d = lane; d < DIM; d += 64) { float v = loadF(xs, xq, r, i, d); p += v * v; }
    p = wsum(p);
    if (lane == 0) sm.fnorm[i] = p;
  }
  if (tid < NSUP) sm.ysl[tid] = ys[r * NSUP + tid];
  for (int idx = tid; idx < WAYS * DIM; idx += 256) {   // proto = mean over shots -> LDS
    int w = idx / DIM, d = idx % DIM;
    float sacc = 0.f;
#pragma unroll
    for (int s5 = 0; s5 < SHOT; s5++) sacc += xs[(r * NSUP + w * SHOT + s5) * DIM + d];
    sm.pbuf[idx] = sacc / 5.0f;
  }
  __syncthreads();

  // Gram tile assignment, ANTI-SPILL split: 210 threads, 2 per symmetric 8x8
  // tile pair (hcol = column half). acc is 32 floats so the (j) inner loop
  // and the (j2) overlap with Areg[56] both fit the 128-VGPR budget.
  int ti = 0, tj = 0;
  if (tid < 210) {
    int t = tid >> 1;
    while (t >= NTILE - ti) { t -= NTILE - ti; ti++; }
    tj = ti + t;
  }
  const int hcol = tid & 1;
  // GJ row ownership: 210 threads, each owns 56 columns of one row
  const bool own = tid < 210;
  const int erow = own ? (tid % 105) : 0;
  const int hh = own ? (tid / 105) : 0;
  const int jbase = HALF * hh;

  float (*band)[112] = (float (*)[112])sm.fch;   // alias; fch dead when band live

  for (int ep = 0; ep < 3; ep++) {
    // (a) proto norms
    for (int w = wid; w < WAYS; w += 4) {
      float p = 0.f;
      for (int d = lane; d < DIM; d += 64) { float v = sm.pbuf[w * DIM + d]; p += v * v; }
      p = wsum(p);
      if (lane == 0) sm.pn[w] = p;
    }
    __syncthreads();
    // (b) M = exp(-lam*d2(query, proto)) into Zm rows 25..99
    for (int pq = wid; pq < NQ * WAYS; pq += 4) {
      int q = pq / 5, w = pq % 5;
      float dt = 0.f;
      for (int d = lane; d < DIM; d += 64)
        dt += xq[(r * NQ + q) * DIM + d] * sm.pbuf[w * DIM + d];
      dt = wsum(dt);
      if (lane == 0) {
        float d2 = fmaxf(sm.fnorm[NSUP + q] + sm.pn[w] - 2.0f * dt, 0.0f);
        sm.Zm[(NSUP + q) * 5 + w] = expf(-LAMB * d2);
      }
    }
    __syncthreads();
    // (c) sinkhorn on queries: n=75, c=15, no labels
    sinkhorn_wave(sm, ctl, bi, NSUP, NQ, 15.0f, false, tid, r, sidx);
    // (d) support rows = onehot(ys)
    if (tid < NSUP * 5) { int i = tid / 5, w = tid % 5; sm.Zm[i * 5 + w] = (sm.ysl[i] == w) ? 1.0f : 0.0f; }
    __syncthreads();
    // (e) entropy + scale Z by (1-ent)
    if (tid < N0) {
      float e = entropy5(&sm.Zm[tid * 5]);
      sm.ent[tid] = e;
      float f1 = 1.0f - e;
#pragma unroll
      for (int w = 0; w < 5; w++) sm.Zm[tid * 5 + w] *= f1;
    }
    __syncthreads();
    // (f) new_proto = Z^T f / Zsum ; proto = 0.4 proto + 0.6 new
    float zs[5];
#pragma unroll
    for (int w = 0; w < 5; w++) zs[w] = bsum(tid < N0 ? sm.Zm[tid * 5 + w] : 0.f, sm.red, tid);
    for (int d = tid; d < DIM; d += 256) {
      float a[5] = {0.f, 0.f, 0.f, 0.f, 0.f};
      for (int i = 0; i < N0; i++) {
        float v = loadF(xs, xq, r, i, d);
#pragma unroll
        for (int w = 0; w < 5; w++) a[w] += sm.Zm[i * 5 + w] * v;
      }
#pragma unroll
      for (int w = 0; w < 5; w++) {
        float old = sm.pbuf[w * DIM + d];
        sm.pbuf[w * DIM + d] = (1.0f - UPD) * old + UPD * (a[w] / zs[w]);
      }
    }
    __syncthreads();
    // proto norms on updated proto
    for (int w = wid; w < WAYS; w += 4) {
      float p = 0.f;
      for (int d = lane; d < DIM; d += 64) { float v = sm.pbuf[w * DIM + d]; p += v * v; }
      p = wsum(p);
      if (lane == 0) sm.pn[w] = p;
    }
    __syncthreads();
    // (g) dist_proto = exp(-lam*d2(proto,proto))
    for (int pp5 = wid; pp5 < 25; pp5 += 4) {
      int a5 = pp5 / 5, b5 = pp5 % 5;
      float dt = 0.f;
      for (int d = lane; d < DIM; d += 64)
        dt += sm.pbuf[a5 * DIM + d] * sm.pbuf[b5 * DIM + d];
      dt = wsum(dt);
      if (lane == 0) {
        float d2 = fmaxf(sm.pn[a5] + sm.pn[b5] - 2.0f * dt, 0.0f);
        sm.dp[pp5] = expf(-LAMB * d2);
      }
    }
    __syncthreads();
    // (h) omega = mean(ent); mask = score < omega
    float omega = bsum(tid < N0 ? sm.ent[tid] : 0.f, sm.red, tid) / 100.0f;
    if (tid < WAYS) {
      float sc = entropy5(&sm.dp[tid * 5]);
      sm.maskv[tid] = (sc < omega) ? 1.0f : 0.0f;
    }
    __syncthreads();
    // (i) extend: fnorm and Z rows 100..104
    if (tid < WAYS) sm.fnorm[N0 + tid] = sm.maskv[tid] * sm.pn[tid];
    if (tid < 25) { int a5 = tid / 5, b5 = tid % 5; sm.Zm[(N0 + a5) * 5 + b5] = sm.dp[tid] * sm.maskv[a5]; }
    __syncthreads();
    // (j) Gram 105x105 via chunked LDS + symmetric 8x4 register tiles (210 thr)
    float acc[32];
#pragma unroll
    for (int z = 0; z < 32; z++) acc[z] = 0.f;
    for (int c = 0; c < 20; c++) {
      for (int idx = tid; idx < FCH_ROWS * 32; idx += 256) {
        int i = idx >> 5, dc = idx & 31;
        float v = 0.f;
        int d = c * 32 + dc;
        if (i < N0) v = loadF(xs, xq, r, i, d);
        else if (i < NF) v = sm.maskv[i - N0] * sm.pbuf[(i - N0) * DIM + d];
        int gg = dc >> 2, rm = dc & 3;
        sm.fch[i * FCH_STRIDE + (((gg ^ ((i >> 3) & 7)) << 2) | rm)] = v;
      }
      __syncthreads();
      if (tid < 210) {
        int i0 = ti * 8, j0 = tj * 8 + 4 * hcol, si = ti & 7, sj = tj & 7;
#pragma unroll
        for (int g = 0; g < 8; g++) {
          float4 a4[8], b4[4];
#pragma unroll
          for (int rr = 0; rr < 8; rr++)
            a4[rr] = *(const float4*)&sm.fch[(i0 + rr) * FCH_STRIDE + ((g ^ si) << 2)];
#pragma unroll
          for (int cc = 0; cc < 4; cc++)
            b4[cc] = *(const float4*)&sm.fch[(j0 + cc) * FCH_STRIDE + ((g ^ sj) << 2)];
#pragma unroll
          for (int rr = 0; rr < 8; rr++)
#pragma unroll
            for (int cc = 0; cc < 4; cc++)
              acc[rr * 4 + cc] += a4[rr].x * b4[cc].x + a4[rr].y * b4[cc].y +
                                  a4[rr].z * b4[cc].z + a4[rr].w * b4[cc].w;
        }
      }
      __syncthreads();
    }
    // (j2) band transfer: Gram tiles -> row-owner registers, fused W transform
    float Areg[HALF];
    float rsum = 0.f;
    for (int b = 0; b < NTILE; b++) {
      if (tid < 210) {
        if (ti == b) {
#pragma unroll
          for (int rr = 0; rr < 8; rr++)
#pragma unroll
            for (int cc = 0; cc < 4; cc++)
              band[rr][8 * tj + 4 * hcol + cc] = acc[rr * 4 + cc];
        }
        if (tj == b && ti != b) {
#pragma unroll
          for (int rr = 0; rr < 8; rr++)
#pragma unroll
            for (int cc = 0; cc < 4; cc++)
              band[4 * hcol + cc][8 * ti + rr] = acc[rr * 4 + cc];
        }
      }
      __syncthreads();
      if (own && (erow >> 3) == b) {
        int lr = erow & 7;
#pragma unroll
        for (int jj = 0; jj < HALF; jj++) {
          int j = jbase + jj;
          float wv = 0.f;
          if (j < NF && j != erow) {
            float d2 = fmaxf(sm.fnorm[erow] + sm.fnorm[j] - 2.0f * band[lr][j], 0.0f);
            wv = expf(-LAMB * d2);
          }
          Areg[jj] = wv;
          rsum += wv;
        }
      }
      __syncthreads();
    }
    // Dm = rowsum(W)^(-1/2)
    if (own && hh == 1) sm.rsumh[erow] = rsum;
    __syncthreads();
    if (own && hh == 0) sm.dm[erow] = 1.0f / sqrtf(rsum + sm.rsumh[erow]);
    __syncthreads();
    // A = I - alpha * (Dm_j * W * Dm_i)  (in registers)
    float cnext = 0.f;
    if (own) {
      float dme = sm.dm[erow];
#pragma unroll
      for (int jj = 0; jj < HALF; jj++) {
        int j = jbase + jj;
        float t = (j < NF) ? (sm.dm[j] * Areg[jj]) * dme : 0.f;
        Areg[jj] = ((j == erow) ? 1.0f : 0.0f) - ALF * t;
      }
      if (hh == 0) cnext = Areg[0];   // column 0 for step k=0
    }
    if (tid < 112) sm.rowk[tid] = 0.f;
    __syncthreads();
    // (l) Gauss-Jordan in registers: [A | Zm] -> Zm = A^{-1} Zm
    for (int k = 0; k < NF; k++) {
      int hk = (k < HALF) ? 0 : 1;
      // phase A: publish pivot column (colk[k]=0 makes row k a no-op in phase C)
      if (own && hh == hk) {
        if (erow == k) { sm.pivotv = cnext; sm.colk[k] = 0.f; }
        else sm.colk[erow] = cnext;
      }
      __syncthreads();
      // phase B: scale pivot row cols >k, publish to rowk
      float pinv = 1.0f / sm.pivotv;
      if (own && erow == k) {
#pragma unroll
        for (int jj = 0; jj < HALF; jj++) {
          int j = jbase + jj;
          if (j > k && j < NF) { Areg[jj] *= pinv; sm.rowk[j] = Areg[jj]; }
        }
        if (hh == hk) sm.rowk[k] = 0.f;
        if (hh == 0) {
#pragma unroll
          for (int w = 0; w < 5; w++) sm.Zm[k * 5 + w] *= pinv;
        }
      }
      __syncthreads();
      // phase C: eliminate; stale rowk at cols<k only touches dead Areg slots
      if (own) {
        float m = sm.colk[erow];
#pragma unroll
        for (int jj = 0; jj < HALF; jj += 4) {
          float4 rk = *(const float4*)&sm.rowk[jbase + jj];
          Areg[jj + 0] -= m * rk.x;
          Areg[jj + 1] -= m * rk.y;
          Areg[jj + 2] -= m * rk.z;
          Areg[jj + 3] -= m * rk.w;
        }
#pragma unroll
        for (int jj = 0; jj < HALF; jj++)
          if (jbase + jj == k + 1) cnext = Areg[jj];
        if (hh == 0 && erow != k) {
#pragma unroll
          for (int w = 0; w < 5; w++) sm.Zm[erow * 5 + w] -= m * sm.Zm[k * 5 + w];
        }
      }
      __syncthreads();
    }
    // (m) final sinkhorn: n=105, c=21, clamp first 25 rows to onehot
    sinkhorn_wave(sm, ctl, bi, 0, NF, 21.0f, true, tid, r, sidx);
  }

  // argmax over queries (first-max ties like jnp.argmax), accuracy out
  float mt = 0.f;
  if (tid < NQ) {
    int row = NSUP + tid;
    float best = sm.Zm[row * 5]; int bl = 0;
#pragma unroll
    for (int w = 1; w < 5; w++) { float v = sm.Zm[row * 5 + w]; if (v > best) { best = v; bl = w; } }
    mt = (yq[r * NQ + tid] == bl) ? 1.0f : 0.0f;
  }
  float tot = bsum(mt, sm.red, tid);
  if (tid == 0) out[r] = tot / 75.0f;
}

extern "C" void kernel_launch(void* const* d_in, const int* in_sizes, int n_in,
                              void* d_out, int out_size, void* d_ws, size_t ws_size,
                              hipStream_t stream) {
  const float* xs = (const float*)d_in[0];
  const float* xq = (const float*)d_in[1];
  const int* ys = (const int*)d_in[2];
  const int* yq = (const int*)d_in[3];
  float* out = (float*)d_out;
  unsigned* ctl = (unsigned*)d_ws;   // padded barrier/wake/slot region, 16 KB
  init_kernel<<<dim3(16), dim3(256), 0, stream>>>(ctl, out);
  fsl_kernel<<<dim3(RUNS), dim3(256), 0, stream>>>(xs, xq, ys, yq, out, ctl);
}

// Round 5
// 6863.911 us; speedup vs baseline: 1.0571x; 1.0571x over previous
//
#include <hip/hip_runtime.h>
#include <math.h>

// Problem constants (from reference)
#define RUNS  512
#define WAYS  5
#define SHOT  5
#define NSUP  25      // NS = WAYS*SHOT
#define NQ    75      // QS = WAYS*QUERIES
#define N0    100     // NS+QS
#define NF    105     // N0 + WAYS (extended with add_proto)
#define DIM   640
#define LAMB  10.0f
#define ALF   0.7f
#define UPD   0.6f
#define OT_EPSF 0.001f
#define OT_MAXIT 1000

#define NTILE 14          // ceil(105/8)
#define FCH_ROWS 112      // NTILE*8
#define FCH_STRIDE 36     // 32 dims + pad, multiple of 4 for float4
#define HALF 56           // GJ column-half width (2*56 >= 105, 56%4==0)
#define CHUNK 64          // sinkhorn trajectory chunk (bits in one ull)

// ---- workspace layout (words; everything line-padded, 16 KB total) ----
#define W_WAKE(g)  ((g) * 16)
#define W_C1(g)    (1024 + (g) * 16)
#define W_C2(s)    (2048 + (s) * 16)
#define W_C0       2176
#define W_SLOT(b,g) (2304 + ((b) * 16 + (g)) * 16)

struct __align__(16) Smem {
  float fch[FCH_ROWS * FCH_STRIDE]; // 4032 f @0 (16B aligned); reused as band[8][112]
  float pbuf[WAYS * DIM];           // 3200: prototypes live in LDS
  float rowk[112];                  // GJ: scaled pivot row
  float colk[112];                  // GJ: pivot column (colk[k]=0 trick)
  float Zm[NF * WAYS];              // 525
  float ent[NF];
  float fnorm[112];
  float dm[112];
  float rsumh[112];
  float dp[WAYS * WAYS];
  float pn[WAYS];
  float maskv[WAYS];
  float red[4];
  float snap[16][44];               // sinkhorn chunk snapshot (p[7][5] + u[7] per owner lane)
  float pivotv;
  int foundsh;
  int ysl[NSUP];
};
static_assert(sizeof(Smem) <= 40 * 1024, "LDS: 2 blocks/CU (80KB of 160KB)");

__device__ __forceinline__ float wsum(float v) {
#pragma unroll
  for (int o = 32; o > 0; o >>= 1) v += __shfl_xor(v, o, 64);
  return v;
}
// Deterministic block reductions (fixed tree order; NO float atomics)
__device__ __forceinline__ float bsum(float v, float* red, int tid) {
  v = wsum(v);
  __syncthreads();                   // WAR protection on red
  if ((tid & 63) == 0) red[tid >> 6] = v;
  __syncthreads();
  return (red[0] + red[1]) + (red[2] + red[3]);
}

// ---- pure-DPP 16-lane all-reduce (VALU-speed, no LDS ops) ----
// Generators: quad_perm(1,0,3,2)=0xB1 (xor1), quad_perm(2,3,0,1)=0x4E (xor2),
// row_half_mirror=0x141 (== xor7 on uniform quads -> adds other quad),
// row_mirror=0x140 (== xor15 -> adds other 8-group). After the 4 steps all
// 16 lanes hold bitwise-identical sums (commutativity => same value per
// level), so duplicate lane groups stay in lockstep.
template <int CTRL>
__device__ __forceinline__ float dppx(float v) {
  union U { float f; int i; } a, b;
  a.f = v;
  b.i = __builtin_amdgcn_update_dpp(0, a.i, CTRL, 0xF, 0xF, true);
  return b.f;
}
__device__ __forceinline__ float rsum16(float v) {
  v += dppx<0xB1>(v);
  v += dppx<0x4E>(v);
  v += dppx<0x141>(v);
  v += dppx<0x140>(v);
  return v;
}
__device__ __forceinline__ float rmax16(float v) {
  v = fmaxf(v, dppx<0xB1>(v));
  v = fmaxf(v, dppx<0x4E>(v));
  v = fmaxf(v, dppx<0x141>(v));
  v = fmaxf(v, dppx<0x140>(v));
  return v;
}

// ---- contention-free grid barrier with found-broadcast (unchanged r2) ----
__device__ __forceinline__ void gbar_found(Smem& sm, unsigned* ctl, unsigned& bi,
                                           int tid, int r, int buf, int base) {
  __syncthreads();
  if (tid == 0) {
    const unsigned tgt = 8u * bi + 7u;
    const unsigned seq = bi + 1u;
    int found = -1;
    bool isroot = false;
    unsigned a = __hip_atomic_fetch_add(&ctl[W_C1(r >> 3)], 1u,
                                        __ATOMIC_RELEASE, __HIP_MEMORY_SCOPE_AGENT);
    if (a == tgt) {
      unsigned b = __hip_atomic_fetch_add(&ctl[W_C2(r >> 6)], 1u,
                                          __ATOMIC_RELEASE, __HIP_MEMORY_SCOPE_AGENT);
      if (b == tgt) {
        unsigned c = __hip_atomic_fetch_add(&ctl[W_C0], 1u,
                                            __ATOMIC_RELEASE, __HIP_MEMORY_SCOPE_AGENT);
        if (c == tgt) isroot = true;
      }
    }
    if (isroot) {
      unsigned long long m = 0ull;
#pragma unroll
      for (int g = 0; g < 16; g++)
        m |= __hip_atomic_load((unsigned long long*)(ctl + W_SLOT(buf, g)),
                               __ATOMIC_RELAXED, __HIP_MEMORY_SCOPE_AGENT);
      for (int p = 0; p < CHUNK; p++) {
        int k = base + p + 1;
        bool cond = (((m >> p) & 1ull) != 0ull) && (k <= OT_MAXIT);
        if (!cond) { found = p; break; }
      }
#pragma unroll
      for (int g = 0; g < 16; g++)
        __hip_atomic_store((unsigned long long*)(ctl + W_SLOT(buf, g)), 0ull,
                           __ATOMIC_RELAXED, __HIP_MEMORY_SCOPE_AGENT);
      unsigned pk = seq | ((unsigned)(found + 1) << 16);
      __hip_atomic_store(&ctl[W_WAKE(0)], pk, __ATOMIC_RELEASE, __HIP_MEMORY_SCOPE_AGENT);
#pragma unroll 4
      for (int g = 1; g < 64; g++)
        __hip_atomic_store(&ctl[W_WAKE(g)], pk, __ATOMIC_RELAXED, __HIP_MEMORY_SCOPE_AGENT);
    } else {
      unsigned w;
      for (;;) {
        w = __hip_atomic_load(&ctl[W_WAKE(r >> 3)], __ATOMIC_RELAXED, __HIP_MEMORY_SCOPE_AGENT);
        if ((w & 0xffffu) >= seq) break;
        __builtin_amdgcn_s_sleep(8);
      }
      found = (int)((w >> 16) & 0xffu) - 1;
    }
    sm.foundsh = found;
    bi++;
  }
  __syncthreads();
}

// entropy per reference compute_entropy on a 5-vector (stride 1)
__device__ __forceinline__ float entropy5(const float* z) {
  float p[5]; float t = 0.f;
#pragma unroll
  for (int w = 0; w < 5; w++) { p[w] = z[w] + 1e-12f; t += p[w]; }
  float H = 0.f;
#pragma unroll
  for (int w = 0; w < 5; w++) { float q = p[w] / t; H -= q * logf(q); }
  return H / logf(5.0f);
}

__device__ __forceinline__ float loadF(const float* xs, const float* xq, int r, int i, int d) {
  return (i < NSUP) ? xs[(r * NSUP + i) * DIM + d] : xq[(r * NQ + (i - NSUP)) * DIM + d];
}

// ---- Materialized-P Sinkhorn, 16-lane DPP layout ----
// EXACT reference per-iteration arithmetic (r1-proven): rowsum (sequential
// 5-add), res = max|u - t|, u=t, p *= (1.0f/t) [exact IEEE div], colsum,
// p *= (cval/cs) [exact IEEE div], clamp support rows to onehot EVERY
// iteration (CLAMP). No rcp, no scaling-form state (r4's clamp/inv bug gone).
// Layout: slot k holds row 16k+(lane&15); lanes 16-63 duplicate lanes 0-15
// (reductions via rsum16/rmax16 produce bitwise-identical values on all
// lanes, keeping duplicates in lockstep). Snapshot/replay state = p,u in
// LDS (sm.snap), written/read by wave 0 only, once per 64-body chunk.
// Chunk/OR-slot/barrier protocol identical to r2.
template <int S, bool CLAMP>
__device__ void sinkhorn_dpp(Smem& sm, unsigned* ctl, unsigned& bi, int rowOff,
                             int n, float cval, int tid, int r, int& sidx) {
  const int lane = tid & 63;
  const int wv = tid >> 6;
  const int l16 = lane & 15;
  const bool grp0 = lane < 16;
  float p[S][5], u[S];
  int yv[S];
  bool val[S];
  if (wv == 0) {
#pragma unroll
    for (int k = 0; k < S; k++) {
      int rr = 16 * k + l16;
      val[k] = rr < n;
#pragma unroll
      for (int w = 0; w < 5; w++)
        p[k][w] = val[k] ? sm.Zm[(rowOff + rr) * 5 + w] : 0.f;
      u[k] = 0.f;
      yv[k] = (CLAMP && rr < NSUP) ? sm.ysl[rr < NSUP ? rr : 0] : -1;
    }
  }

  // body: returns res (cond residual BEFORE this body); then applies exactly
  // one reference iteration (row-norm, col-norm, clamp).
  auto body = [&]() -> float {
    float res = 0.f;
#pragma unroll
    for (int k = 0; k < S; k++) {
      float t = p[k][0];
#pragma unroll
      for (int w = 1; w < 5; w++) t += p[k][w];
      res = fmaxf(res, val[k] ? fabsf(u[k] - t) : 0.f);
      u[k] = t;
      float i0 = val[k] ? 1.0f / t : 0.f;   // exact IEEE divide (no fast-math)
#pragma unroll
      for (int w = 0; w < 5; w++) p[k][w] *= i0;
    }
    res = rmax16(res);
#pragma unroll
    for (int w = 0; w < 5; w++) {
      float cs = p[0][w];
#pragma unroll
      for (int k = 1; k < S; k++) cs += p[k][w];
      cs = rsum16(cs);
      float f = cval / cs;                  // exact IEEE divide
#pragma unroll
      for (int k = 0; k < S; k++) p[k][w] *= f;
    }
    if (CLAMP) {
#pragma unroll
      for (int k = 0; k < S; k++) {
        if (16 * k < NSUP) {                // compile-time prune (k=0,1 only)
          if (yv[k] >= 0) {
#pragma unroll
            for (int w = 0; w < 5; w++) p[k][w] = (yv[k] == w) ? 1.0f : 0.0f;
          }
        }
      }
    }
    return res;
  };

  int base = 0;
  while (true) {
    unsigned long long mask = 0ull;
    if (wv == 0) {
      if (grp0) {   // snapshot state after `base` bodies -> LDS
#pragma unroll
        for (int k = 0; k < S; k++) {
#pragma unroll
          for (int w = 0; w < 5; w++) sm.snap[l16][k * 5 + w] = p[k][w];
          sm.snap[l16][35 + k] = u[k];
        }
      }
#pragma unroll 1
      for (int pp = 0; pp < CHUNK; pp++) {
        float res = body();
        if (res > OT_EPSF) mask |= (1ull << pp);
      }
      if (lane == 0)
        __hip_atomic_fetch_or((unsigned long long*)(ctl + W_SLOT(sidx & 1, r >> 5)), mask,
                              __ATOMIC_RELAXED, __HIP_MEMORY_SCOPE_AGENT);
    }
    gbar_found(sm, ctl, bi, tid, r, sidx & 1, base);
    int found = sm.foundsh;
    sidx++;
    if (found >= 0) {
      if (wv == 0) {
        // restore snapshot (all 64 lanes re-read -> duplicates resync),
        // replay exactly `found` bodies (total = base+found)
#pragma unroll
        for (int k = 0; k < S; k++) {
#pragma unroll
          for (int w = 0; w < 5; w++) p[k][w] = sm.snap[l16][k * 5 + w];
          u[k] = sm.snap[l16][35 + k];
        }
#pragma unroll 1
        for (int pp = 0; pp < found; pp++) (void)body();
        if (grp0) {
#pragma unroll
          for (int k = 0; k < S; k++) {
            if (val[k]) {
              int rr = 16 * k + l16;
#pragma unroll
              for (int w = 0; w < 5; w++)
                sm.Zm[(rowOff + rr) * 5 + w] = p[k][w];
            }
          }
        }
      }
      __syncthreads();
      return;
    }
    base += CHUNK;
  }
}

// init: zero barrier words + slots (16 KB region); sentinel out=-1
__global__ void init_kernel(unsigned* __restrict__ ctl, float* __restrict__ out) {
  int i = blockIdx.x * blockDim.x + threadIdx.x;
  if (i < 4096) __hip_atomic_store(&ctl[i], 0u, __ATOMIC_RELAXED, __HIP_MEMORY_SCOPE_AGENT);
  if (i < RUNS) out[i] = -1.0f;
}

__global__ __launch_bounds__(256, 2) void fsl_kernel(
    const float* __restrict__ xs, const float* __restrict__ xq,
    const int* __restrict__ ys, const int* __restrict__ yq,
    float* __restrict__ out, unsigned* __restrict__ ctl) {
  __shared__ Smem sm;
  const int tid = threadIdx.x;
  const int r = blockIdx.x;
  const int lane = tid & 63, wid = tid >> 6;
  unsigned bi = 0;
  int sidx = 0;

  // ---- persistent precompute ----
  for (int i = wid; i < N0; i += 4) {     // |f_i|^2, constant across epochs
    float p = 0.f;
    for (int d = lane; d < DIM; d += 64) { float v = loadF(xs, xq, r, i, d); p += v * v; }
    p = wsum(p);
    if (lane == 0) sm.fnorm[i] = p;
  }
  if (tid < NSUP) sm.ysl[tid] = ys[r * NSUP + tid];
  for (int idx = tid; idx < WAYS * DIM; idx += 256) {   // proto = mean over shots -> LDS
    int w = idx / DIM, d = idx % DIM;
    float sacc = 0.f;
#pragma unroll
    for (int s5 = 0; s5 < SHOT; s5++) sacc += xs[(r * NSUP + w * SHOT + s5) * DIM + d];
    sm.pbuf[idx] = sacc / 5.0f;
  }
  __syncthreads();

  // Gram tile assignment, ANTI-SPILL split: 210 threads, 2 per symmetric 8x8
  // tile pair (hcol = column half). acc is 32 floats so the (j) inner loop
  // and the (j2) overlap with Areg[56] both fit the 128-VGPR budget.
  int ti = 0, tj = 0;
  if (tid < 210) {
    int t = tid >> 1;
    while (t >= NTILE - ti) { t -= NTILE - ti; ti++; }
    tj = ti + t;
  }
  const int hcol = tid & 1;
  // GJ row ownership: 210 threads, each owns 56 columns of one row
  const bool own = tid < 210;
  const int erow = own ? (tid % 105) : 0;
  const int hh = own ? (tid / 105) : 0;
  const int jbase = HALF * hh;

  float (*band)[112] = (float (*)[112])sm.fch;   // alias; fch dead when band live

  for (int ep = 0; ep < 3; ep++) {
    // (a) proto norms
    for (int w = wid; w < WAYS; w += 4) {
      float p = 0.f;
      for (int d = lane; d < DIM; d += 64) { float v = sm.pbuf[w * DIM + d]; p += v * v; }
      p = wsum(p);
      if (lane == 0) sm.pn[w] = p;
    }
    __syncthreads();
    // (b) M = exp(-lam*d2(query, proto)) into Zm rows 25..99
    for (int pq = wid; pq < NQ * WAYS; pq += 4) {
      int q = pq / 5, w = pq % 5;
      float dt = 0.f;
      for (int d = lane; d < DIM; d += 64)
        dt += xq[(r * NQ + q) * DIM + d] * sm.pbuf[w * DIM + d];
      dt = wsum(dt);
      if (lane == 0) {
        float d2 = fmaxf(sm.fnorm[NSUP + q] + sm.pn[w] - 2.0f * dt, 0.0f);
        sm.Zm[(NSUP + q) * 5 + w] = expf(-LAMB * d2);
      }
    }
    __syncthreads();
    // (c) sinkhorn on queries: n=75, c=15, no labels
    sinkhorn_dpp<5, false>(sm, ctl, bi, NSUP, NQ, 15.0f, tid, r, sidx);
    // (d) support rows = onehot(ys)
    if (tid < NSUP * 5) { int i = tid / 5, w = tid % 5; sm.Zm[i * 5 + w] = (sm.ysl[i] == w) ? 1.0f : 0.0f; }
    __syncthreads();
    // (e) entropy + scale Z by (1-ent)
    if (tid < N0) {
      float e = entropy5(&sm.Zm[tid * 5]);
      sm.ent[tid] = e;
      float f1 = 1.0f - e;
#pragma unroll
      for (int w = 0; w < 5; w++) sm.Zm[tid * 5 + w] *= f1;
    }
    __syncthreads();
    // (f) new_proto = Z^T f / Zsum ; proto = 0.4 proto + 0.6 new
    float zs[5];
#pragma unroll
    for (int w = 0; w < 5; w++) zs[w] = bsum(tid < N0 ? sm.Zm[tid * 5 + w] : 0.f, sm.red, tid);
    for (int d = tid; d < DIM; d += 256) {
      float a[5] = {0.f, 0.f, 0.f, 0.f, 0.f};
      for (int i = 0; i < N0; i++) {
        float v = loadF(xs, xq, r, i, d);
#pragma unroll
        for (int w = 0; w < 5; w++) a[w] += sm.Zm[i * 5 + w] * v;
      }
#pragma unroll
      for (int w = 0; w < 5; w++) {
        float old = sm.pbuf[w * DIM + d];
        sm.pbuf[w * DIM + d] = (1.0f - UPD) * old + UPD * (a[w] / zs[w]);
      }
    }
    __syncthreads();
    // proto norms on updated proto
    for (int w = wid; w < WAYS; w += 4) {
      float p = 0.f;
      for (int d = lane; d < DIM; d += 64) { float v = sm.pbuf[w * DIM + d]; p += v * v; }
      p = wsum(p);
      if (lane == 0) sm.pn[w] = p;
    }
    __syncthreads();
    // (g) dist_proto = exp(-lam*d2(proto,proto))
    for (int pp5 = wid; pp5 < 25; pp5 += 4) {
      int a5 = pp5 / 5, b5 = pp5 % 5;
      float dt = 0.f;
      for (int d = lane; d < DIM; d += 64)
        dt += sm.pbuf[a5 * DIM + d] * sm.pbuf[b5 * DIM + d];
      dt = wsum(dt);
      if (lane == 0) {
        float d2 = fmaxf(sm.pn[a5] + sm.pn[b5] - 2.0f * dt, 0.0f);
        sm.dp[pp5] = expf(-LAMB * d2);
      }
    }
    __syncthreads();
    // (h) omega = mean(ent); mask = score < omega
    float omega = bsum(tid < N0 ? sm.ent[tid] : 0.f, sm.red, tid) / 100.0f;
    if (tid < WAYS) {
      float sc = entropy5(&sm.dp[tid * 5]);
      sm.maskv[tid] = (sc < omega) ? 1.0f : 0.0f;
    }
    __syncthreads();
    // (i) extend: fnorm and Z rows 100..104
    if (tid < WAYS) sm.fnorm[N0 + tid] = sm.maskv[tid] * sm.pn[tid];
    if (tid < 25) { int a5 = tid / 5, b5 = tid % 5; sm.Zm[(N0 + a5) * 5 + b5] = sm.dp[tid] * sm.maskv[a5]; }
    __syncthreads();
    // (j) Gram 105x105 via chunked LDS + symmetric 8x4 register tiles (210 thr)
    float acc[32];
#pragma unroll
    for (int z = 0; z < 32; z++) acc[z] = 0.f;
    for (int c = 0; c < 20; c++) {
      for (int idx = tid; idx < FCH_ROWS * 32; idx += 256) {
        int i = idx >> 5, dc = idx & 31;
        float v = 0.f;
        int d = c * 32 + dc;
        if (i < N0) v = loadF(xs, xq, r, i, d);
        else if (i < NF) v = sm.maskv[i - N0] * sm.pbuf[(i - N0) * DIM + d];
        int gg = dc >> 2, rm = dc & 3;
        sm.fch[i * FCH_STRIDE + (((gg ^ ((i >> 3) & 7)) << 2) | rm)] = v;
      }
      __syncthreads();
      if (tid < 210) {
        int i0 = ti * 8, j0 = tj * 8 + 4 * hcol, si = ti & 7, sj = tj & 7;
#pragma unroll
        for (int g = 0; g < 8; g++) {
          float4 a4[8], b4[4];
#pragma unroll
          for (int rr = 0; rr < 8; rr++)
            a4[rr] = *(const float4*)&sm.fch[(i0 + rr) * FCH_STRIDE + ((g ^ si) << 2)];
#pragma unroll
          for (int cc = 0; cc < 4; cc++)
            b4[cc] = *(const float4*)&sm.fch[(j0 + cc) * FCH_STRIDE + ((g ^ sj) << 2)];
#pragma unroll
          for (int rr = 0; rr < 8; rr++)
#pragma unroll
            for (int cc = 0; cc < 4; cc++)
              acc[rr * 4 + cc] += a4[rr].x * b4[cc].x + a4[rr].y * b4[cc].y +
                                  a4[rr].z * b4[cc].z + a4[rr].w * b4[cc].w;
        }
      }
      __syncthreads();
    }
    // (j2) band transfer: Gram tiles -> row-owner registers, fused W transform
    float Areg[HALF];
    float rsum = 0.f;
    for (int b = 0; b < NTILE; b++) {
      if (tid < 210) {
        if (ti == b) {
#pragma unroll
          for (int rr = 0; rr < 8; rr++)
#pragma unroll
            for (int cc = 0; cc < 4; cc++)
              band[rr][8 * tj + 4 * hcol + cc] = acc[rr * 4 + cc];
        }
        if (tj == b && ti != b) {
#pragma unroll
          for (int rr = 0; rr < 8; rr++)
#pragma unroll
            for (int cc = 0; cc < 4; cc++)
              band[4 * hcol + cc][8 * ti + rr] = acc[rr * 4 + cc];
        }
      }
      __syncthreads();
      if (own && (erow >> 3) == b) {
        int lr = erow & 7;
#pragma unroll
        for (int jj = 0; jj < HALF; jj++) {
          int j = jbase + jj;
          float wv = 0.f;
          if (j < NF && j != erow) {
            float d2 = fmaxf(sm.fnorm[erow] + sm.fnorm[j] - 2.0f * band[lr][j], 0.0f);
            wv = expf(-LAMB * d2);
          }
          Areg[jj] = wv;
          rsum += wv;
        }
      }
      __syncthreads();
    }
    // Dm = rowsum(W)^(-1/2)
    if (own && hh == 1) sm.rsumh[erow] = rsum;
    __syncthreads();
    if (own && hh == 0) sm.dm[erow] = 1.0f / sqrtf(rsum + sm.rsumh[erow]);
    __syncthreads();
    // A = I - alpha * (Dm_j * W * Dm_i)  (in registers)
    float cnext = 0.f;
    if (own) {
      float dme = sm.dm[erow];
#pragma unroll
      for (int jj = 0; jj < HALF; jj++) {
        int j = jbase + jj;
        float t = (j < NF) ? (sm.dm[j] * Areg[jj]) * dme : 0.f;
        Areg[jj] = ((j == erow) ? 1.0f : 0.0f) - ALF * t;
      }
      if (hh == 0) cnext = Areg[0];   // column 0 for step k=0
    }
    if (tid < 112) sm.rowk[tid] = 0.f;
    __syncthreads();
    // (l) Gauss-Jordan in registers: [A | Zm] -> Zm = A^{-1} Zm
    for (int k = 0; k < NF; k++) {
      int hk = (k < HALF) ? 0 : 1;
      // phase A: publish pivot column (colk[k]=0 makes row k a no-op in phase C)
      if (own && hh == hk) {
        if (erow == k) { sm.pivotv = cnext; sm.colk[k] = 0.f; }
        else sm.colk[erow] = cnext;
      }
      __syncthreads();
      // phase B: scale pivot row cols >k, publish to rowk
      float pinv = 1.0f / sm.pivotv;
      if (own && erow == k) {
#pragma unroll
        for (int jj = 0; jj < HALF; jj++) {
          int j = jbase + jj;
          if (j > k && j < NF) { Areg[jj] *= pinv; sm.rowk[j] = Areg[jj]; }
        }
        if (hh == hk) sm.rowk[k] = 0.f;
        if (hh == 0) {
#pragma unroll
          for (int w = 0; w < 5; w++) sm.Zm[k * 5 + w] *= pinv;
        }
      }
      __syncthreads();
      // phase C: eliminate; stale rowk at cols<k only touches dead Areg slots
      if (own) {
        float m = sm.colk[erow];
#pragma unroll
        for (int jj = 0; jj < HALF; jj += 4) {
          float4 rk = *(const float4*)&sm.rowk[jbase + jj];
          Areg[jj + 0] -= m * rk.x;
          Areg[jj + 1] -= m * rk.y;
          Areg[jj + 2] -= m * rk.z;
          Areg[jj + 3] -= m * rk.w;
        }
#pragma unroll
        for (int jj = 0; jj < HALF; jj++)
          if (jbase + jj == k + 1) cnext = Areg[jj];
        if (hh == 0 && erow != k) {
#pragma unroll
          for (int w = 0; w < 5; w++) sm.Zm[erow * 5 + w] -= m * sm.Zm[k * 5 + w];
        }
      }
      __syncthreads();
    }
    // (m) final sinkhorn: n=105, c=21, clamp first 25 rows to onehot
    sinkhorn_dpp<7, true>(sm, ctl, bi, 0, NF, 21.0f, tid, r, sidx);
  }

  // argmax over queries (first-max ties like jnp.argmax), accuracy out
  float mt = 0.f;
  if (tid < NQ) {
    int row = NSUP + tid;
    float best = sm.Zm[row * 5]; int bl = 0;
#pragma unroll
    for (int w = 1; w < 5; w++) { float v = sm.Zm[row * 5 + w]; if (v > best) { best = v; bl = w; } }
    mt = (yq[r * NQ + tid] == bl) ? 1.0f : 0.0f;
  }
  float tot = bsum(mt, sm.red, tid);
  if (tid == 0) out[r] = tot / 75.0f;
}

extern "C" void kernel_launch(void* const* d_in, const int* in_sizes, int n_in,
                              void* d_out, int out_size, void* d_ws, size_t ws_size,
                              hipStream_t stream) {
  const float* xs = (const float*)d_in[0];
  const float* xq = (const float*)d_in[1];
  const int* ys = (const int*)d_in[2];
  const int* yq = (const int*)d_in[3];
  float* out = (float*)d_out;
  unsigned* ctl = (unsigned*)d_ws;   // padded barrier/wake/slot region, 16 KB
  init_kernel<<<dim3(16), dim3(256), 0, stream>>>(ctl, out);
  fsl_kernel<<<dim3(RUNS), dim3(256), 0, stream>>>(xs, xq, ys, yq, out, ctl);
}